// Round 13
// baseline (414.943 us; speedup 1.0000x reference)
//
#include <hip/hip_runtime.h>

// DigiCaps dynamic routing — recompute, clean LDS staging, occupancy-tuned.
// inputs [512,1152,8] f32, W [10,1152,16,8] f32, out v [512,10,16] f32.
// u_hat[b,j,i,d] = sum_k x[b,i,k] W[j,i,d,k]; logits b_t = u_hat . vsum
// (vsum = running sum of v's) -> u_hat never materialized.
//
// R12 forensics: traffic clean (16MB/11.5MB), but MODE0==MODE1==46us ->
// pass is common-path bound (staging latency + ds_read->MFMA chains) at
// only 2 blocks/CU (57.9KB LDS) + ragged 64-block tail. R13: 8-i blocks
// -> 28.7KB LDS -> 5 blocks/CU (20 waves), grid (8,144)=1152 (4.5/CU,
// smooth). Epilogue bounce in bf16 (partials are bf16 anyway). Body is
// the R12-verified code. MFMA f32_16x16x32_bf16, C-layout: lane&15=b,
// (lane>>4)*4+reg=d; A: kg==0 lanes carry W k=0..7, kg>0 read zeroed
// granule -> exact K=8. absmax ~4e-3 (threshold 17.5e-3).

#define NB 512
#define NI 1152
#define NJ 10
#define ND 16

typedef short          bf16x8 __attribute__((ext_vector_type(8)));
typedef unsigned short u16x8  __attribute__((ext_vector_type(8)));
typedef float          f32x4  __attribute__((ext_vector_type(4)));

constexpr float EPS_ = 1e-7f;

constexpr size_t XB_ELEMS = (size_t)NB * NI * 8;       // bf16
constexpr size_t WB_ELEMS = (size_t)NJ * NI * ND * 8;  // bf16
constexpr int    XQ = 1179648;                         // x float4 quads
constexpr int    WQ = 368640;                          // W float4 quads
constexpr int    NIGB = 144;                           // i-groups of 8

__device__ inline unsigned short f2bf(float f) {   // RNE f32->bf16
    unsigned u = __float_as_uint(f);
    return (unsigned short)((u + 0x7fffu + ((u >> 16) & 1u)) >> 16);
}
__device__ inline float bf2f(unsigned short u) {
    return __uint_as_float((unsigned)u << 16);
}

__global__ __launch_bounds__(256)
void conv_bf16(const float* __restrict__ x, const float* __restrict__ Wg,
               unsigned short* __restrict__ xb, unsigned short* __restrict__ wb)
{
    int t = blockIdx.x * 256 + threadIdx.x;
    if (t < XQ) {
        float4 v = ((const float4*)x)[t];
        ushort4 o; o.x=f2bf(v.x); o.y=f2bf(v.y); o.z=f2bf(v.z); o.w=f2bf(v.w);
        ((ushort4*)xb)[t] = o;
    } else if (t - XQ < WQ) {
        int u = t - XQ;
        float4 v = ((const float4*)Wg)[u];
        ushort4 o; o.x=f2bf(v.x); o.y=f2bf(v.y); o.z=f2bf(v.z); o.w=f2bf(v.w);
        ((ushort4*)wb)[u] = o;
    }
}

// Block: 64 b (4 waves x 16) x 8 i. Full tile staged upfront (one barrier),
// K-loop fully LDS-fed. LDS 28.7KB -> 5 blocks/CU.
template <int MODE>
__global__ __launch_bounds__(256, 5)
void caps_pass(const unsigned short* __restrict__ xb,
               const unsigned short* __restrict__ wb,
               const float* __restrict__ vsum_g,
               unsigned short* __restrict__ part)
{
    // smem (bytes): [0,20480) wl 1280 granules [il][j][d];
    // [20480,28672) xl 512 granules (XOR-swizzled); [28672,28688) zp.
    // Epilogue re-uses [0,21504) as bf16 s16[64][168].
    __shared__ __align__(16) char smem[28688];
    unsigned short* wl = (unsigned short*)smem;
    unsigned short* xl = (unsigned short*)(smem + 20480);
    unsigned short* zp = (unsigned short*)(smem + 28672);

    const int tid = threadIdx.x, lane = tid & 63, w = tid >> 6;
    const int bl = lane & 15, kg = lane >> 4;
    const int bg = blockIdx.x, ig = blockIdx.y;
    const int i0 = ig * 8, b0 = bg * 64;
    const int b  = b0 + w * 16 + bl;
    const int brow = w * 16 + bl;

    if (tid < 8) zp[tid] = 0;

    // stage W: granule g = il*160 + j*16 + d <- wb[j, i0+il, d, 0:8]
#pragma unroll
    for (int r = 0; r < 5; ++r) {
        int g  = tid + r * 256;
        int il = g / 160, rem = g - il * 160;
        const unsigned short* src =
            wb + ((size_t)(rem >> 4) * NI + (i0 + il)) * 128 + (rem & 15) * 8;
        *(u16x8*)(wl + g * 8) = *(const u16x8*)src;
    }
    // stage x: slot (br*8+sg) holds x[b0+br, i0 + (sg^(br&7)), 0:8]
#pragma unroll
    for (int r = 0; r < 2; ++r) {
        int g  = tid + r * 256;
        int br = g >> 3, sg = g & 7;
        int gr = sg ^ (br & 7);
        *(u16x8*)(xl + g * 8) =
            *(const u16x8*)(xb + ((size_t)(b0 + br) * NI + i0 + gr) * 8);
    }

    f32x4 vs[NJ];
    if (MODE == 1) {
#pragma unroll
        for (int j = 0; j < NJ; ++j)
            vs[j] = *(const f32x4*)(vsum_g + (size_t)b * 160 + j * 16 + kg * 4);
    }

    __syncthreads();

    const f32x4 zero = {0.f, 0.f, 0.f, 0.f};
    f32x4 sacc[NJ];
#pragma unroll
    for (int j = 0; j < NJ; ++j) sacc[j] = zero;

#pragma unroll 2
    for (int it = 0; it < 8; ++it) {
        bf16x8 xv = *(const bf16x8*)(xl + (brow * 8 + (it ^ (brow & 7))) * 8);

        f32x4 uh[NJ];
#pragma unroll
        for (int j = 0; j < NJ; ++j) {
            const unsigned short* ap = (kg == 0)
                ? (wl + ((it * 10 + j) * 16 + bl) * 8) : zp;
            bf16x8 af = *(const bf16x8*)ap;
            if (MODE == 0)
                sacc[j] = __builtin_amdgcn_mfma_f32_16x16x32_bf16(af, xv, sacc[j], 0, 0, 0);
            else
                uh[j] = __builtin_amdgcn_mfma_f32_16x16x32_bf16(af, xv, zero, 0, 0, 0);
        }

        if (MODE == 1) {
            float bd[NJ];
#pragma unroll
            for (int j = 0; j < NJ; ++j) {
                float v = uh[j][0] * vs[j][0] + uh[j][1] * vs[j][1]
                        + uh[j][2] * vs[j][2] + uh[j][3] * vs[j][3];
                v += __shfl_xor(v, 16, 64);   // reduce the 4 d-quads
                v += __shfl_xor(v, 32, 64);
                bd[j] = v;
            }
            float m01 = fmaxf(bd[0], bd[1]), m23 = fmaxf(bd[2], bd[3]);
            float m45 = fmaxf(bd[4], bd[5]), m67 = fmaxf(bd[6], bd[7]);
            float m89 = fmaxf(bd[8], bd[9]);
            float m = fmaxf(fmaxf(fmaxf(m01, m23), fmaxf(m45, m67)), m89);
#pragma unroll
            for (int j = 0; j < NJ; ++j) bd[j] = __expf(bd[j] - m);
            float Z = ((bd[0] + bd[1]) + (bd[2] + bd[3]))
                    + ((bd[4] + bd[5]) + (bd[6] + bd[7])) + (bd[8] + bd[9]);
            const float rZ = 1.f / Z;
#pragma unroll
            for (int j = 0; j < NJ; ++j) {
                const float c = bd[j] * rZ;
                sacc[j] += c * uh[j];
            }
        }
    }

    // epilogue: sacc -> bf16 LDS bounce -> dense contiguous bf16 partials
    __syncthreads();
    unsigned short* s16 = (unsigned short*)smem;   // [64][168]
#pragma unroll
    for (int j = 0; j < NJ; ++j) {
        ushort4 o;
        o.x = f2bf(sacc[j][0]); o.y = f2bf(sacc[j][1]);
        o.z = f2bf(sacc[j][2]); o.w = f2bf(sacc[j][3]);
        *(ushort4*)(s16 + brow * 168 + j * 16 + kg * 4) = o;
    }
    __syncthreads();
    unsigned short* pp = part + ((size_t)ig * NB + b0) * 160;
#pragma unroll
    for (int r = 0; r < 5; ++r) {
        int idx = tid + r * 256;                 // 1280 ushort8 chunks = 64x160
        int row = idx / 20, ch = idx - row * 20;
        *(u16x8*)(pp + idx * 8) = *(const u16x8*)(s16 + row * 168 + ch * 8);
    }
}

// Sum 144 bf16 ig-partials, scale, squash over d (16-lane shfl), update vsum/out.
__global__ __launch_bounds__(256)
void squash_reduce(const unsigned short* __restrict__ part,
                   float* __restrict__ vsum_g, float* __restrict__ out,
                   float alpha, int mode)
{
    const int t = blockIdx.x * 256 + threadIdx.x;   // < 81920 = b*160 + j*16 + d
    const unsigned short* p = part + t;
    float a0 = 0.f, a1 = 0.f, a2 = 0.f, a3 = 0.f;
#pragma unroll 4
    for (int ig = 0; ig < NIGB; ig += 4) {
        a0 += bf2f(p[(size_t)ig * 81920]);
        a1 += bf2f(p[(size_t)(ig + 1) * 81920]);
        a2 += bf2f(p[(size_t)(ig + 2) * 81920]);
        a3 += bf2f(p[(size_t)(ig + 3) * 81920]);
    }
    const float s = ((a0 + a1) + (a2 + a3)) * alpha;

    float sq = s * s;
    sq += __shfl_xor(sq, 1, 64);
    sq += __shfl_xor(sq, 2, 64);
    sq += __shfl_xor(sq, 4, 64);
    sq += __shfl_xor(sq, 8, 64);
    const float sc = sq / ((1.f + sq) * sqrtf(sq + EPS_));
    const float v  = sc * s;

    if (mode == 0)      vsum_g[t] = v;
    else if (mode == 1) vsum_g[t] += v;
    else                out[t] = v;
}

extern "C" void kernel_launch(void* const* d_in, const int* in_sizes, int n_in,
                              void* d_out, int out_size, void* d_ws, size_t ws_size,
                              hipStream_t stream)
{
    const float* inp = (const float*)d_in[0];
    const float* Wg  = (const float*)d_in[1];
    float* out = (float*)d_out;

    unsigned short* xbp  = (unsigned short*)d_ws;
    unsigned short* wbp  = xbp + XB_ELEMS;
    unsigned short* part = wbp + WB_ELEMS;                    // [144][512][160] bf16
    float* vsum = (float*)(part + (size_t)NIGB * NB * 160);   // [512][10][16] f32

    conv_bf16<<<(XQ + WQ + 255) / 256, 256, 0, stream>>>(inp, Wg, xbp, wbp);

    dim3 grid(8, NIGB);   // (8,144) = 1152 blocks, ~4.5/CU, 5 resident by LDS
    // iter 0: c uniform 1/10 (folded into alpha)
    caps_pass<0><<<grid, 256, 0, stream>>>(xbp, wbp, nullptr, part);
    squash_reduce<<<320, 256, 0, stream>>>(part, vsum, out, 0.1f, 0);
    // iter 1: logits = u_hat . v0
    caps_pass<1><<<grid, 256, 0, stream>>>(xbp, wbp, vsum, part);
    squash_reduce<<<320, 256, 0, stream>>>(part, vsum, out, 1.0f, 1);
    // iter 2: logits = u_hat . (v0+v1)
    caps_pass<1><<<grid, 256, 0, stream>>>(xbp, wbp, vsum, part);
    squash_reduce<<<320, 256, 0, stream>>>(part, vsum, out, 1.0f, 2);
}

// Round 14
// 166.719 us; speedup vs baseline: 2.4889x; 2.4889x over previous
//
#include <hip/hip_runtime.h>

// DigiCaps dynamic routing — recompute, clean LDS staging, occupancy-tuned v2.
// inputs [512,1152,8] f32, W [10,1152,16,8] f32, out v [512,10,16] f32.
// u_hat[b,j,i,d] = sum_k x[b,i,k] W[j,i,d,k]; logits b_t = u_hat . vsum
// (vsum = running sum of v's) -> u_hat never materialized.
//
// R13 forensics: __launch_bounds__(256,5) made the allocator pick 48 VGPRs
// against a ~120-reg working set -> scratch spills (283MB FETCH / 418MB
// WRITE of pure spill traffic; VALUBusy 0.26% on MODE0). Same signature as
// the R8-R10 "phantom" — it was spills all along. R12's (256,2) -> 88 VGPR,
// zero spill, clean 16/11.5MB. R14 = R13's 8-i / 28.7KB-LDS tile (5
// blocks/CU by LDS; launch_bounds 2nd arg is only a minimum — HW residency
// comes from resources) + R12's (256,2) register policy.
// MFMA f32_16x16x32_bf16, C-layout: lane&15=b, (lane>>4)*4+reg=d; A: kg==0
// lanes carry W k=0..7, kg>0 read zeroed granule -> exact K=8. absmax ~4e-3.

#define NB 512
#define NI 1152
#define NJ 10
#define ND 16

typedef short          bf16x8 __attribute__((ext_vector_type(8)));
typedef unsigned short u16x8  __attribute__((ext_vector_type(8)));
typedef float          f32x4  __attribute__((ext_vector_type(4)));

constexpr float EPS_ = 1e-7f;

constexpr size_t XB_ELEMS = (size_t)NB * NI * 8;       // bf16
constexpr size_t WB_ELEMS = (size_t)NJ * NI * ND * 8;  // bf16
constexpr int    XQ = 1179648;                         // x float4 quads
constexpr int    WQ = 368640;                          // W float4 quads
constexpr int    NIGB = 144;                           // i-groups of 8

__device__ inline unsigned short f2bf(float f) {   // RNE f32->bf16
    unsigned u = __float_as_uint(f);
    return (unsigned short)((u + 0x7fffu + ((u >> 16) & 1u)) >> 16);
}
__device__ inline float bf2f(unsigned short u) {
    return __uint_as_float((unsigned)u << 16);
}

__global__ __launch_bounds__(256)
void conv_bf16(const float* __restrict__ x, const float* __restrict__ Wg,
               unsigned short* __restrict__ xb, unsigned short* __restrict__ wb)
{
    int t = blockIdx.x * 256 + threadIdx.x;
    if (t < XQ) {
        float4 v = ((const float4*)x)[t];
        ushort4 o; o.x=f2bf(v.x); o.y=f2bf(v.y); o.z=f2bf(v.z); o.w=f2bf(v.w);
        ((ushort4*)xb)[t] = o;
    } else if (t - XQ < WQ) {
        int u = t - XQ;
        float4 v = ((const float4*)Wg)[u];
        ushort4 o; o.x=f2bf(v.x); o.y=f2bf(v.y); o.z=f2bf(v.z); o.w=f2bf(v.w);
        ((ushort4*)wb)[u] = o;
    }
}

// Block: 64 b (4 waves x 16) x 8 i. Full tile staged upfront (one barrier),
// K-loop fully LDS-fed. LDS 28.7KB -> 5 blocks/CU by LDS; (256,2) keeps the
// allocator at the proven no-spill ~88-VGPR point.
template <int MODE>
__global__ __launch_bounds__(256, 2)
void caps_pass(const unsigned short* __restrict__ xb,
               const unsigned short* __restrict__ wb,
               const float* __restrict__ vsum_g,
               unsigned short* __restrict__ part)
{
    // smem (bytes): [0,20480) wl 1280 granules [il][j][d];
    // [20480,28672) xl 512 granules (XOR-swizzled); [28672,28688) zp.
    // Epilogue re-uses [0,21504) as bf16 s16[64][168].
    __shared__ __align__(16) char smem[28688];
    unsigned short* wl = (unsigned short*)smem;
    unsigned short* xl = (unsigned short*)(smem + 20480);
    unsigned short* zp = (unsigned short*)(smem + 28672);

    const int tid = threadIdx.x, lane = tid & 63, w = tid >> 6;
    const int bl = lane & 15, kg = lane >> 4;
    const int bg = blockIdx.x, ig = blockIdx.y;
    const int i0 = ig * 8, b0 = bg * 64;
    const int b  = b0 + w * 16 + bl;
    const int brow = w * 16 + bl;

    if (tid < 8) zp[tid] = 0;

    // stage W: granule g = il*160 + j*16 + d <- wb[j, i0+il, d, 0:8]
#pragma unroll
    for (int r = 0; r < 5; ++r) {
        int g  = tid + r * 256;
        int il = g / 160, rem = g - il * 160;
        const unsigned short* src =
            wb + ((size_t)(rem >> 4) * NI + (i0 + il)) * 128 + (rem & 15) * 8;
        *(u16x8*)(wl + g * 8) = *(const u16x8*)src;
    }
    // stage x: slot (br*8+sg) holds x[b0+br, i0 + (sg^(br&7)), 0:8]
#pragma unroll
    for (int r = 0; r < 2; ++r) {
        int g  = tid + r * 256;
        int br = g >> 3, sg = g & 7;
        int gr = sg ^ (br & 7);
        *(u16x8*)(xl + g * 8) =
            *(const u16x8*)(xb + ((size_t)(b0 + br) * NI + i0 + gr) * 8);
    }

    f32x4 vs[NJ];
    if (MODE == 1) {
#pragma unroll
        for (int j = 0; j < NJ; ++j)
            vs[j] = *(const f32x4*)(vsum_g + (size_t)b * 160 + j * 16 + kg * 4);
    }

    __syncthreads();

    const f32x4 zero = {0.f, 0.f, 0.f, 0.f};
    f32x4 sacc[NJ];
#pragma unroll
    for (int j = 0; j < NJ; ++j) sacc[j] = zero;

#pragma unroll 2
    for (int it = 0; it < 8; ++it) {
        bf16x8 xv = *(const bf16x8*)(xl + (brow * 8 + (it ^ (brow & 7))) * 8);

        f32x4 uh[NJ];
#pragma unroll
        for (int j = 0; j < NJ; ++j) {
            const unsigned short* ap = (kg == 0)
                ? (wl + ((it * 10 + j) * 16 + bl) * 8) : zp;
            bf16x8 af = *(const bf16x8*)ap;
            if (MODE == 0)
                sacc[j] = __builtin_amdgcn_mfma_f32_16x16x32_bf16(af, xv, sacc[j], 0, 0, 0);
            else
                uh[j] = __builtin_amdgcn_mfma_f32_16x16x32_bf16(af, xv, zero, 0, 0, 0);
        }

        if (MODE == 1) {
            float bd[NJ];
#pragma unroll
            for (int j = 0; j < NJ; ++j) {
                float v = uh[j][0] * vs[j][0] + uh[j][1] * vs[j][1]
                        + uh[j][2] * vs[j][2] + uh[j][3] * vs[j][3];
                v += __shfl_xor(v, 16, 64);   // reduce the 4 d-quads
                v += __shfl_xor(v, 32, 64);
                bd[j] = v;
            }
            float m01 = fmaxf(bd[0], bd[1]), m23 = fmaxf(bd[2], bd[3]);
            float m45 = fmaxf(bd[4], bd[5]), m67 = fmaxf(bd[6], bd[7]);
            float m89 = fmaxf(bd[8], bd[9]);
            float m = fmaxf(fmaxf(fmaxf(m01, m23), fmaxf(m45, m67)), m89);
#pragma unroll
            for (int j = 0; j < NJ; ++j) bd[j] = __expf(bd[j] - m);
            float Z = ((bd[0] + bd[1]) + (bd[2] + bd[3]))
                    + ((bd[4] + bd[5]) + (bd[6] + bd[7])) + (bd[8] + bd[9]);
            const float rZ = 1.f / Z;
#pragma unroll
            for (int j = 0; j < NJ; ++j) {
                const float c = bd[j] * rZ;
                sacc[j] += c * uh[j];
            }
        }
    }

    // epilogue: sacc -> bf16 LDS bounce -> dense contiguous bf16 partials
    __syncthreads();
    unsigned short* s16 = (unsigned short*)smem;   // [64][168]
#pragma unroll
    for (int j = 0; j < NJ; ++j) {
        ushort4 o;
        o.x = f2bf(sacc[j][0]); o.y = f2bf(sacc[j][1]);
        o.z = f2bf(sacc[j][2]); o.w = f2bf(sacc[j][3]);
        *(ushort4*)(s16 + brow * 168 + j * 16 + kg * 4) = o;
    }
    __syncthreads();
    unsigned short* pp = part + ((size_t)ig * NB + b0) * 160;
#pragma unroll
    for (int r = 0; r < 5; ++r) {
        int idx = tid + r * 256;                 // 1280 ushort8 chunks = 64x160
        int row = idx / 20, ch = idx - row * 20;
        *(u16x8*)(pp + idx * 8) = *(const u16x8*)(s16 + row * 168 + ch * 8);
    }
}

// Sum 144 bf16 ig-partials, scale, squash over d (16-lane shfl), update vsum/out.
__global__ __launch_bounds__(256)
void squash_reduce(const unsigned short* __restrict__ part,
                   float* __restrict__ vsum_g, float* __restrict__ out,
                   float alpha, int mode)
{
    const int t = blockIdx.x * 256 + threadIdx.x;   // < 81920 = b*160 + j*16 + d
    const unsigned short* p = part + t;
    float a0 = 0.f, a1 = 0.f, a2 = 0.f, a3 = 0.f;
#pragma unroll 4
    for (int ig = 0; ig < NIGB; ig += 4) {
        a0 += bf2f(p[(size_t)ig * 81920]);
        a1 += bf2f(p[(size_t)(ig + 1) * 81920]);
        a2 += bf2f(p[(size_t)(ig + 2) * 81920]);
        a3 += bf2f(p[(size_t)(ig + 3) * 81920]);
    }
    const float s = ((a0 + a1) + (a2 + a3)) * alpha;

    float sq = s * s;
    sq += __shfl_xor(sq, 1, 64);
    sq += __shfl_xor(sq, 2, 64);
    sq += __shfl_xor(sq, 4, 64);
    sq += __shfl_xor(sq, 8, 64);
    const float sc = sq / ((1.f + sq) * sqrtf(sq + EPS_));
    const float v  = sc * s;

    if (mode == 0)      vsum_g[t] = v;
    else if (mode == 1) vsum_g[t] += v;
    else                out[t] = v;
}

extern "C" void kernel_launch(void* const* d_in, const int* in_sizes, int n_in,
                              void* d_out, int out_size, void* d_ws, size_t ws_size,
                              hipStream_t stream)
{
    const float* inp = (const float*)d_in[0];
    const float* Wg  = (const float*)d_in[1];
    float* out = (float*)d_out;

    unsigned short* xbp  = (unsigned short*)d_ws;
    unsigned short* wbp  = xbp + XB_ELEMS;
    unsigned short* part = wbp + WB_ELEMS;                    // [144][512][160] bf16
    float* vsum = (float*)(part + (size_t)NIGB * NB * 160);   // [512][10][16] f32

    conv_bf16<<<(XQ + WQ + 255) / 256, 256, 0, stream>>>(inp, Wg, xbp, wbp);

    dim3 grid(8, NIGB);   // (8,144) = 1152 blocks; LDS allows 5 blocks/CU
    // iter 0: c uniform 1/10 (folded into alpha)
    caps_pass<0><<<grid, 256, 0, stream>>>(xbp, wbp, nullptr, part);
    squash_reduce<<<320, 256, 0, stream>>>(part, vsum, out, 0.1f, 0);
    // iter 1: logits = u_hat . v0
    caps_pass<1><<<grid, 256, 0, stream>>>(xbp, wbp, vsum, part);
    squash_reduce<<<320, 256, 0, stream>>>(part, vsum, out, 1.0f, 1);
    // iter 2: logits = u_hat . (v0+v1)
    caps_pass<1><<<grid, 256, 0, stream>>>(xbp, wbp, vsum, part);
    squash_reduce<<<320, 256, 0, stream>>>(part, vsum, out, 1.0f, 2);
}

// Round 15
// 163.819 us; speedup vs baseline: 2.5329x; 1.0177x over previous
//
#include <hip/hip_runtime.h>

// DigiCaps dynamic routing — recompute, K=32-packed LDS A-frags + B-masking.
// inputs [512,1152,8] f32, W [10,1152,16,8] f32, out v [512,10,16] f32.
// u_hat[b,j,i,d] = sum_k x[b,i,k] W[j,i,d,k]; logits b_t = u_hat . vsum
// (vsum = running sum of v's) -> u_hat never materialized.
//
// R12/R14 forensics: passes stall-bound at ~40us vs ~15us pipe floor, with
// MODE0==MODE1 -> the shared cost is the LDS read stream (44 ds_read_b128
// per wave per 4 i's at K=8, 3/4 of each A-read feeding zero-lanes) + a
// 16-way bank conflict on the xv read (128B-stride rows). R15: pack 4 i's
// into MFMA K (lane (kg,bl) holds W[i4+kg, j, d=bl] -> 10 A-reads per 4 i,
// all 64 lanes real). MODE0 contracts K=32 directly (exact); MODE1 isolates
// i=q by masking B (kg==q ? xv : 0, 4 cndmask). wl il-stride padded to 161
// granules (kg-groups on distinct bank quads), xl rows padded to 9 granules
// (xv conflict-free). Register policy (256,2) — the proven no-spill point.
// MFMA f32_16x16x32_bf16, C-layout: lane&15=b(col), (lane>>4)*4+reg=d(row).
// absmax ~4e-3 (threshold 17.5e-3).

#define NB 512
#define NI 1152
#define NJ 10
#define ND 16

typedef short          bf16x8 __attribute__((ext_vector_type(8)));
typedef unsigned short u16x8  __attribute__((ext_vector_type(8)));
typedef float          f32x4  __attribute__((ext_vector_type(4)));

constexpr float EPS_ = 1e-7f;

constexpr size_t XB_ELEMS = (size_t)NB * NI * 8;       // bf16
constexpr size_t WB_ELEMS = (size_t)NJ * NI * ND * 8;  // bf16
constexpr int    XQ = 1179648;                         // x float4 quads
constexpr int    WQ = 368640;                          // W float4 quads
constexpr int    NIGB = 144;                           // i-groups of 8

__device__ inline unsigned short f2bf(float f) {   // RNE f32->bf16
    unsigned u = __float_as_uint(f);
    return (unsigned short)((u + 0x7fffu + ((u >> 16) & 1u)) >> 16);
}
__device__ inline float bf2f(unsigned short u) {
    return __uint_as_float((unsigned)u << 16);
}

__global__ __launch_bounds__(256)
void conv_bf16(const float* __restrict__ x, const float* __restrict__ Wg,
               unsigned short* __restrict__ xb, unsigned short* __restrict__ wb)
{
    int t = blockIdx.x * 256 + threadIdx.x;
    if (t < XQ) {
        float4 v = ((const float4*)x)[t];
        ushort4 o; o.x=f2bf(v.x); o.y=f2bf(v.y); o.z=f2bf(v.z); o.w=f2bf(v.w);
        ((ushort4*)xb)[t] = o;
    } else if (t - XQ < WQ) {
        int u = t - XQ;
        float4 v = ((const float4*)Wg)[u];
        ushort4 o; o.x=f2bf(v.x); o.y=f2bf(v.y); o.z=f2bf(v.z); o.w=f2bf(v.w);
        ((ushort4*)wb)[u] = o;
    }
}

// Block: 64 b (4 waves x 16) x 8 i (two 4-i K-packs). LDS ~30KB.
template <int MODE>
__global__ __launch_bounds__(256, 2)
void caps_pass(const unsigned short* __restrict__ xb,
               const unsigned short* __restrict__ wb,
               const float* __restrict__ vsum_g,
               unsigned short* __restrict__ part)
{
    // wl: granule g = il*161 + j*16 + d (8 rows of 161, pad granule breaks
    // the 2560B kg-group aliasing). xl: row stride 9 granules (144B -> banks
    // rotate by 4 per row). Epilogue reuses [0,21504) as bf16 s16[64][168].
    __shared__ __align__(16) char smem[30368];
    unsigned short* wl = (unsigned short*)smem;                 // 1288 granules
    unsigned short* xl = (unsigned short*)(smem + 20608);       // 576 granules
    // [29824, 30368) slack

    const int tid = threadIdx.x, lane = tid & 63, w = tid >> 6;
    const int bl = lane & 15, kg = lane >> 4;
    const int bg = blockIdx.x, ig = blockIdx.y;
    const int i0 = ig * 8, b0 = bg * 64;
    const int b  = b0 + w * 16 + bl;
    const int brow = w * 16 + bl;

    // stage W: 1280 real granules -> slot il*161 + rem
#pragma unroll
    for (int r = 0; r < 5; ++r) {
        int g  = tid + r * 256;
        int il = g / 160, rem = g - il * 160;
        const unsigned short* src =
            wb + ((size_t)(rem >> 4) * NI + (i0 + il)) * 128 + (rem & 15) * 8;
        *(u16x8*)(wl + (il * 161 + rem) * 8) = *(const u16x8*)src;
    }
    // stage x: slot brow*9 + il  <-  x[b0+brow, i0+il, 0:8]
#pragma unroll
    for (int r = 0; r < 2; ++r) {
        int g = tid + r * 256;
        if (g < 512) {
            int br = g >> 3, il = g & 7;
            *(u16x8*)(xl + (br * 9 + il) * 8) =
                *(const u16x8*)(xb + ((size_t)(b0 + br) * NI + i0 + il) * 8);
        }
    }

    f32x4 vs[NJ];
    if (MODE == 1) {
#pragma unroll
        for (int j = 0; j < NJ; ++j)
            vs[j] = *(const f32x4*)(vsum_g + (size_t)b * 160 + j * 16 + kg * 4);
    }

    __syncthreads();

    const f32x4  zero  = {0.f, 0.f, 0.f, 0.f};
    const bf16x8 zerob = {0, 0, 0, 0, 0, 0, 0, 0};
    f32x4 sacc[NJ];
#pragma unroll
    for (int j = 0; j < NJ; ++j) sacc[j] = zero;

#pragma unroll
    for (int t4 = 0; t4 < 2; ++t4) {
        // A-frags: lane (kg,bl) = W[i0+t4*4+kg, j, d=bl, 0:8] — K=32 packed,
        // all 64 lanes real; 10 reads per FOUR i's.
        bf16x8 afull[NJ];
#pragma unroll
        for (int j = 0; j < NJ; ++j)
            afull[j] = *(const bf16x8*)(wl + (((t4 * 4 + kg) * 161) + j * 16 + bl) * 8);

        if (MODE == 0) {
            // xv packed the same way: lane (kg,bl) = x[b of bl-group? no —
            // B-frag n=b needs lane's own b and its kg-th i. row = brow.
            bf16x8 xv = *(const bf16x8*)(xl + (brow * 9 + t4 * 4 + kg) * 8);
#pragma unroll
            for (int j = 0; j < NJ; ++j)
                sacc[j] = __builtin_amdgcn_mfma_f32_16x16x32_bf16(afull[j], xv, sacc[j], 0, 0, 0);
        } else {
            bf16x8 xv = *(const bf16x8*)(xl + (brow * 9 + t4 * 4 + kg) * 8);
#pragma unroll
            for (int q = 0; q < 4; ++q) {
                const bf16x8 bq = (kg == q) ? xv : zerob;   // isolate i = i0+t4*4+q
                f32x4 uh[NJ];
#pragma unroll
                for (int j = 0; j < NJ; ++j)
                    uh[j] = __builtin_amdgcn_mfma_f32_16x16x32_bf16(afull[j], bq, zero, 0, 0, 0);

                float bd[NJ];
#pragma unroll
                for (int j = 0; j < NJ; ++j) {
                    float v = uh[j][0] * vs[j][0] + uh[j][1] * vs[j][1]
                            + uh[j][2] * vs[j][2] + uh[j][3] * vs[j][3];
                    v += __shfl_xor(v, 16, 64);   // reduce the 4 d-quads
                    v += __shfl_xor(v, 32, 64);
                    bd[j] = v;
                }
                float m01 = fmaxf(bd[0], bd[1]), m23 = fmaxf(bd[2], bd[3]);
                float m45 = fmaxf(bd[4], bd[5]), m67 = fmaxf(bd[6], bd[7]);
                float m89 = fmaxf(bd[8], bd[9]);
                float m = fmaxf(fmaxf(fmaxf(m01, m23), fmaxf(m45, m67)), m89);
#pragma unroll
                for (int j = 0; j < NJ; ++j) bd[j] = __expf(bd[j] - m);
                float Z = ((bd[0] + bd[1]) + (bd[2] + bd[3]))
                        + ((bd[4] + bd[5]) + (bd[6] + bd[7])) + (bd[8] + bd[9]);
                const float rZ = 1.f / Z;
#pragma unroll
                for (int j = 0; j < NJ; ++j) {
                    const float c = bd[j] * rZ;
                    sacc[j] += c * uh[j];
                }
            }
        }
    }

    // epilogue: sacc -> bf16 LDS bounce -> dense contiguous bf16 partials
    __syncthreads();
    unsigned short* s16 = (unsigned short*)smem;   // [64][168]
#pragma unroll
    for (int j = 0; j < NJ; ++j) {
        ushort4 o;
        o.x = f2bf(sacc[j][0]); o.y = f2bf(sacc[j][1]);
        o.z = f2bf(sacc[j][2]); o.w = f2bf(sacc[j][3]);
        *(ushort4*)(s16 + brow * 168 + j * 16 + kg * 4) = o;
    }
    __syncthreads();
    unsigned short* pp = part + ((size_t)ig * NB + b0) * 160;
#pragma unroll
    for (int r = 0; r < 5; ++r) {
        int idx = tid + r * 256;                 // 1280 ushort8 chunks = 64x160
        int row = idx / 20, ch = idx - row * 20;
        *(u16x8*)(pp + idx * 8) = *(const u16x8*)(s16 + row * 168 + ch * 8);
    }
}

// Sum 144 bf16 ig-partials, scale, squash over d (16-lane shfl), update vsum/out.
__global__ __launch_bounds__(256)
void squash_reduce(const unsigned short* __restrict__ part,
                   float* __restrict__ vsum_g, float* __restrict__ out,
                   float alpha, int mode)
{
    const int t = blockIdx.x * 256 + threadIdx.x;   // < 81920 = b*160 + j*16 + d
    const unsigned short* p = part + t;
    float a0 = 0.f, a1 = 0.f, a2 = 0.f, a3 = 0.f;
#pragma unroll 4
    for (int ig = 0; ig < NIGB; ig += 4) {
        a0 += bf2f(p[(size_t)ig * 81920]);
        a1 += bf2f(p[(size_t)(ig + 1) * 81920]);
        a2 += bf2f(p[(size_t)(ig + 2) * 81920]);
        a3 += bf2f(p[(size_t)(ig + 3) * 81920]);
    }
    const float s = ((a0 + a1) + (a2 + a3)) * alpha;

    float sq = s * s;
    sq += __shfl_xor(sq, 1, 64);
    sq += __shfl_xor(sq, 2, 64);
    sq += __shfl_xor(sq, 4, 64);
    sq += __shfl_xor(sq, 8, 64);
    const float sc = sq / ((1.f + sq) * sqrtf(sq + EPS_));
    const float v  = sc * s;

    if (mode == 0)      vsum_g[t] = v;
    else if (mode == 1) vsum_g[t] += v;
    else                out[t] = v;
}

extern "C" void kernel_launch(void* const* d_in, const int* in_sizes, int n_in,
                              void* d_out, int out_size, void* d_ws, size_t ws_size,
                              hipStream_t stream)
{
    const float* inp = (const float*)d_in[0];
    const float* Wg  = (const float*)d_in[1];
    float* out = (float*)d_out;

    unsigned short* xbp  = (unsigned short*)d_ws;
    unsigned short* wbp  = xbp + XB_ELEMS;
    unsigned short* part = wbp + WB_ELEMS;                    // [144][512][160] bf16
    float* vsum = (float*)(part + (size_t)NIGB * NB * 160);   // [512][10][16] f32

    conv_bf16<<<(XQ + WQ + 255) / 256, 256, 0, stream>>>(inp, Wg, xbp, wbp);

    dim3 grid(8, NIGB);   // (8,144) = 1152 blocks
    // iter 0: c uniform 1/10 (folded into alpha); K=32 contracts 4 i's exactly
    caps_pass<0><<<grid, 256, 0, stream>>>(xbp, wbp, nullptr, part);
    squash_reduce<<<320, 256, 0, stream>>>(part, vsum, out, 0.1f, 0);
    // iter 1: logits = u_hat . v0
    caps_pass<1><<<grid, 256, 0, stream>>>(xbp, wbp, vsum, part);
    squash_reduce<<<320, 256, 0, stream>>>(part, vsum, out, 1.0f, 1);
    // iter 2: logits = u_hat . (v0+v1)
    caps_pass<1><<<grid, 256, 0, stream>>>(xbp, wbp, vsum, part);
    squash_reduce<<<320, 256, 0, stream>>>(part, vsum, out, 1.0f, 2);
}